// Round 3
// baseline (514.610 us; speedup 1.0000x reference)
//
#include <hip/hip_runtime.h>

#define B_ 128
#define T_ 2048
#define H_ 128
#define WPAD 136  // 128 + 8 pad (bf16 elems) -> breaks 16-way bank conflict on B-frag reads

typedef __attribute__((ext_vector_type(8))) short short8;
typedef __attribute__((ext_vector_type(4))) float f32x4;

__device__ __forceinline__ unsigned short f2b(float f) {
    unsigned int u = __float_as_uint(f);
    u += 0x7fffu + ((u >> 16) & 1u);   // RNE
    return (unsigned short)(u >> 16);
}
__device__ __forceinline__ short8 pack8(const float4 x, const float4 y) {
    short8 r;
    r[0] = (short)f2b(x.x); r[1] = (short)f2b(x.y);
    r[2] = (short)f2b(x.z); r[3] = (short)f2b(x.w);
    r[4] = (short)f2b(y.x); r[5] = (short)f2b(y.y);
    r[6] = (short)f2b(y.z); r[7] = (short)f2b(y.w);
    return r;
}
__device__ __forceinline__ float tanh_fast(float x) {
    x = fminf(fmaxf(x, -20.f), 20.f);
    float e = __expf(2.f * x);
    return (e - 1.f) / (e + 1.f);
}

// ---------------- Phase 1: energy[b,t] = W_a . tanh(W_h hp + W_d hd) + b_a ----
// GEMM rows = b*T+t (M=262144), N=128, K=256 (hp|hd). fp32 in, bf16 MFMA.
// 512 thr (8 waves) share one weight-LDS copy; 2 blocks/CU; VGPR capped 128.
__global__ __launch_bounds__(512, 4) void energy_kernel(
    const float* __restrict__ Hp,
    const float* __restrict__ Hd,
    const float* __restrict__ Wh,
    const float* __restrict__ Wd,
    const float* __restrict__ Wa,
    const float* __restrict__ ba_p,
    float* __restrict__ energy,
    int ntiles)   // tiles of 128 rows
{
    __shared__ unsigned short Whs[H_ * WPAD];   // 34816 B
    __shared__ unsigned short Wds[H_ * WPAD];   // 34816 B
    __shared__ float Was[H_];                   // 512 B

    const int tid = threadIdx.x;

    // stage W_h, W_d (fp32 [o][h]) into padded bf16 LDS
    for (int i = tid; i < (H_ * H_) / 4; i += 512) {
        int row = i >> 5;          // 32 float4 per row
        int c4  = (i & 31) * 4;
        float4 wh = *(const float4*)&Wh[row * H_ + c4];
        float4 wd = *(const float4*)&Wd[row * H_ + c4];
        uint2 ph, pd;
        ph.x = (unsigned)f2b(wh.x) | ((unsigned)f2b(wh.y) << 16);
        ph.y = (unsigned)f2b(wh.z) | ((unsigned)f2b(wh.w) << 16);
        pd.x = (unsigned)f2b(wd.x) | ((unsigned)f2b(wd.y) << 16);
        pd.y = (unsigned)f2b(wd.z) | ((unsigned)f2b(wd.w) << 16);
        *(uint2*)&Whs[row * WPAD + c4] = ph;
        *(uint2*)&Wds[row * WPAD + c4] = pd;
    }
    if (tid < H_) Was[tid] = Wa[tid];
    __syncthreads();

    const float ba = ba_p[0];

    const int wave = tid >> 6;     // 0..7
    const int lane = tid & 63;
    const int l15  = lane & 15;
    const int lq   = lane >> 4;    // 0..3

    for (int tile = blockIdx.x; tile < ntiles; tile += gridDim.x) {
        const int row_base = tile * 128 + wave * 16;

        // A fragments: A[m=l15][k = kt*32 + lq*8 + j]; kt 0..3 = Hp, 4..7 = Hd
        short8 afrag[8];
        const float* ap = Hp + (size_t)(row_base + l15) * H_ + lq * 8;
        const float* ad = Hd + (size_t)(row_base + l15) * H_ + lq * 8;
        #pragma unroll
        for (int kt = 0; kt < 4; kt++) {
            float4 x0 = *(const float4*)(ap + kt * 32);
            float4 x1 = *(const float4*)(ap + kt * 32 + 4);
            afrag[kt] = pack8(x0, x1);
        }
        #pragma unroll
        for (int kt = 0; kt < 4; kt++) {
            float4 y0 = *(const float4*)(ad + kt * 32);
            float4 y1 = *(const float4*)(ad + kt * 32 + 4);
            afrag[kt + 4] = pack8(y0, y1);
        }

        float ep[4] = {0.f, 0.f, 0.f, 0.f};
        #pragma unroll
        for (int nt = 0; nt < 8; nt += 2) {
            const int n0 = nt * 16 + l15;
            const int n1 = n0 + 16;
            f32x4 acc0 = {0.f, 0.f, 0.f, 0.f};
            f32x4 acc1 = {0.f, 0.f, 0.f, 0.f};
            #pragma unroll
            for (int kt = 0; kt < 8; kt++) {
                const unsigned short* ws = (kt < 4) ? Whs : Wds;
                const int kk = (kt & 3) * 32 + lq * 8;
                short8 b0 = *(const short8*)&ws[n0 * WPAD + kk];
                short8 b1 = *(const short8*)&ws[n1 * WPAD + kk];
                acc0 = __builtin_amdgcn_mfma_f32_16x16x32_bf16(afrag[kt], b0, acc0, 0, 0, 0);
                acc1 = __builtin_amdgcn_mfma_f32_16x16x32_bf16(afrag[kt], b1, acc1, 0, 0, 0);
            }
            const float wa0 = Was[n0];
            const float wa1 = Was[n1];
            // C/D: col = lane&15, row = lq*4 + r
            #pragma unroll
            for (int r = 0; r < 4; r++)
                ep[r] += tanh_fast(acc0[r]) * wa0 + tanh_fast(acc1[r]) * wa1;
        }
        #pragma unroll
        for (int m = 1; m < 16; m <<= 1) {
            #pragma unroll
            for (int r = 0; r < 4; r++) ep[r] += __shfl_xor(ep[r], m, 64);
        }
        if (l15 == 0) {
            #pragma unroll
            for (int r = 0; r < 4; r++)
                energy[row_base + lq * 4 + r] = ep[r] + ba;
        }
    }
}

// ---------------- Phase 2a: softmax over T -> alpha (fp32) ----------------
__global__ __launch_bounds__(256) void softmax_kernel(
    const float* __restrict__ accw,
    const float* __restrict__ beta_p,
    const float* __restrict__ energy,
    float* __restrict__ out_alpha)
{
    __shared__ float sred[8];
    const int b    = blockIdx.x;
    const int tid  = threadIdx.x;
    const int lane = tid & 63;
    const int wid  = tid >> 6;   // 0..3

    const float beta_pos = log1pf(__expf(beta_p[0]));

    float av[8], ev[8];
    float amax = -1e30f;
    #pragma unroll
    for (int i = 0; i < 8; i++) {
        int t = i * 256 + tid;
        av[i] = accw[b * T_ + t];
        ev[i] = energy[b * T_ + t];
        amax = fmaxf(amax, av[i]);
    }
    for (int m = 32; m >= 1; m >>= 1) amax = fmaxf(amax, __shfl_xor(amax, m, 64));
    if (lane == 0) sred[wid] = amax;
    __syncthreads();
    if (tid == 0)
        sred[4] = fmaxf(fmaxf(sred[0], sred[1]), fmaxf(sred[2], sred[3]));
    __syncthreads();
    const float invd = beta_pos / fmaxf(sred[4], 1e-6f);

    float sv[8], smax = -1e30f;
    #pragma unroll
    for (int i = 0; i < 8; i++) {
        sv[i] = ev[i] * (1.f + av[i] * invd);
        smax = fmaxf(smax, sv[i]);
    }
    for (int m = 32; m >= 1; m >>= 1) smax = fmaxf(smax, __shfl_xor(smax, m, 64));
    __syncthreads();
    if (lane == 0) sred[wid] = smax;
    __syncthreads();
    if (tid == 0)
        sred[5] = fmaxf(fmaxf(sred[0], sred[1]), fmaxf(sred[2], sred[3]));
    __syncthreads();
    const float smax_all = sred[5];

    float p[8], psum = 0.f;
    #pragma unroll
    for (int i = 0; i < 8; i++) { p[i] = __expf(sv[i] - smax_all); psum += p[i]; }
    for (int m = 32; m >= 1; m >>= 1) psum += __shfl_xor(psum, m, 64);
    __syncthreads();
    if (lane == 0) sred[wid] = psum;
    __syncthreads();
    if (tid == 0)
        sred[6] = sred[0] + sred[1] + sred[2] + sred[3];
    __syncthreads();
    const float invS = 1.f / sred[6];

    #pragma unroll
    for (int i = 0; i < 8; i++)
        out_alpha[b * T_ + i * 256 + tid] = p[i] * invS;
}

// ---------------- Phase 2b: partial context, fully coalesced ----------------
// grid = B*8 blocks; block sl of batch b covers t in [sl*256, sl*256+256).
// 32 consecutive lanes read one full 512B row -> perfect coalescing.
__global__ __launch_bounds__(256) void ctx_partial_kernel(
    const float* __restrict__ Hp,
    const float* __restrict__ alpha,
    float* __restrict__ cpart)   // [B][8][H]
{
    __shared__ float al_s[256];
    __shared__ float red[8 * H_];   // 4 KB

    const int sl  = blockIdx.x & 7;
    const int b   = blockIdx.x >> 3;
    const int tid = threadIdx.x;
    const int row = tid >> 5;      // 0..7
    const int c4  = tid & 31;      // float4 index within row

    al_s[tid] = alpha[b * T_ + sl * 256 + tid];
    __syncthreads();

    float c0 = 0.f, c1 = 0.f, c2 = 0.f, c3 = 0.f;
    const float* base = Hp + ((size_t)b * T_ + sl * 256) * H_ + c4 * 4;
    #pragma unroll 4
    for (int it = 0; it < 32; it++) {
        int t = it * 8 + row;
        float a = al_s[t];
        float4 v = *(const float4*)(base + (size_t)t * H_);
        c0 += a * v.x; c1 += a * v.y; c2 += a * v.z; c3 += a * v.w;
    }
    red[row * H_ + c4 * 4 + 0] = c0;
    red[row * H_ + c4 * 4 + 1] = c1;
    red[row * H_ + c4 * 4 + 2] = c2;
    red[row * H_ + c4 * 4 + 3] = c3;
    __syncthreads();
    if (tid < H_) {
        float s = 0.f;
        #pragma unroll
        for (int g = 0; g < 8; g++) s += red[g * H_ + tid];
        cpart[(b * 8 + sl) * H_ + tid] = s;
    }
}

__global__ __launch_bounds__(256) void ctx_reduce_kernel(
    const float* __restrict__ cpart, float* __restrict__ out_ctx)
{
    int i = blockIdx.x * 256 + threadIdx.x;   // i < B*H
    if (i < B_ * H_) {
        int b = i >> 7, h = i & 127;
        float s = 0.f;
        #pragma unroll
        for (int g = 0; g < 8; g++) s += cpart[(b * 8 + g) * H_ + h];
        out_ctx[i] = s;
    }
}

extern "C" void kernel_launch(void* const* d_in, const int* in_sizes, int n_in,
                              void* d_out, int out_size, void* d_ws, size_t ws_size,
                              hipStream_t stream) {
    const float* Hp   = (const float*)d_in[0];
    const float* Hd   = (const float*)d_in[1];
    const float* accw = (const float*)d_in[2];
    const float* Wh   = (const float*)d_in[3];
    const float* Wd   = (const float*)d_in[4];
    const float* Wa   = (const float*)d_in[5];
    const float* ba   = (const float*)d_in[6];
    const float* beta = (const float*)d_in[7];

    float* energy_ws = (float*)d_ws;                 // B*T fp32 = 1 MB
    float* cpart_ws  = energy_ws + B_ * T_;          // B*8*H fp32 = 512 KB

    float* out_ctx   = (float*)d_out;                // [B,H]
    float* out_alpha = out_ctx + B_ * H_;            // [B,T]

    const int ntiles = (B_ * T_) / 128;   // 2048 tiles of 128 rows
    energy_kernel<<<512, 512, 0, stream>>>(Hp, Hd, Wh, Wd, Wa, ba, energy_ws, ntiles);
    softmax_kernel<<<B_, 256, 0, stream>>>(accw, beta, energy_ws, out_alpha);
    ctx_partial_kernel<<<B_ * 8, 256, 0, stream>>>(Hp, out_alpha, cpart_ws);
    ctx_reduce_kernel<<<(B_ * H_ + 255) / 256, 256, 0, stream>>>(cpart_ws, out_ctx);
}

// Round 4
// 318.412 us; speedup vs baseline: 1.6162x; 1.6162x over previous
//
#include <hip/hip_runtime.h>

#define B_ 128
#define T_ 2048
#define H_ 128
#define WPAD 136  // 128 + 8 pad (bf16): B-frag row stride 272B = 4-bank rotation -> 2-way (free)

typedef __attribute__((ext_vector_type(8))) short short8;
typedef __attribute__((ext_vector_type(4))) float f32x4;

__device__ __forceinline__ unsigned short f2b(float f) {
    unsigned int u = __float_as_uint(f);
    u += 0x7fffu + ((u >> 16) & 1u);   // RNE
    return (unsigned short)(u >> 16);
}
__device__ __forceinline__ short8 pack8(const float4 x, const float4 y) {
    short8 r;
    r[0] = (short)f2b(x.x); r[1] = (short)f2b(x.y);
    r[2] = (short)f2b(x.z); r[3] = (short)f2b(x.w);
    r[4] = (short)f2b(y.x); r[5] = (short)f2b(y.y);
    r[6] = (short)f2b(y.z); r[7] = (short)f2b(y.w);
    return r;
}
__device__ __forceinline__ float tanh_fast(float x) {
    x = fminf(fmaxf(x, -20.f), 20.f);
    float e = __expf(2.f * x);
    return (e - 1.f) / (e + 1.f);
}

// ---------------- Phase 1: energy[b,t] = W_a . tanh(W_h hp + W_d hd) + b_a ----
// GEMM rows = b*T+t (M=262144), N=128, K=256 (hp|hd). fp32 in, bf16 MFMA.
// Loop order: rolled K outer, 8 persistent accumulators inner -> low VGPR, no spill.
__global__ __launch_bounds__(512) void energy_kernel(
    const float* __restrict__ Hp,
    const float* __restrict__ Hd,
    const float* __restrict__ Wh,
    const float* __restrict__ Wd,
    const float* __restrict__ Wa,
    const float* __restrict__ ba_p,
    float* __restrict__ energy,
    int ntiles)   // tiles of 128 rows
{
    __shared__ unsigned short Whs[H_ * WPAD];   // 34816 B
    __shared__ unsigned short Wds[H_ * WPAD];   // 34816 B
    __shared__ float Was[H_];                   // 512 B

    const int tid = threadIdx.x;

    // stage W_h, W_d (fp32 [o][h]) into padded bf16 LDS
    for (int i = tid; i < (H_ * H_) / 4; i += 512) {
        int row = i >> 5;          // 32 float4 per row
        int c4  = (i & 31) * 4;
        float4 wh = *(const float4*)&Wh[row * H_ + c4];
        float4 wd = *(const float4*)&Wd[row * H_ + c4];
        uint2 ph, pd;
        ph.x = (unsigned)f2b(wh.x) | ((unsigned)f2b(wh.y) << 16);
        ph.y = (unsigned)f2b(wh.z) | ((unsigned)f2b(wh.w) << 16);
        pd.x = (unsigned)f2b(wd.x) | ((unsigned)f2b(wd.y) << 16);
        pd.y = (unsigned)f2b(wd.z) | ((unsigned)f2b(wd.w) << 16);
        *(uint2*)&Whs[row * WPAD + c4] = ph;
        *(uint2*)&Wds[row * WPAD + c4] = pd;
    }
    if (tid < H_) Was[tid] = Wa[tid];
    __syncthreads();

    const float ba = ba_p[0];

    const int wave = tid >> 6;     // 0..7
    const int lane = tid & 63;
    const int l15  = lane & 15;
    const int lq   = lane >> 4;    // 0..3

    for (int tile = blockIdx.x; tile < ntiles; tile += gridDim.x) {
        const int row_base = tile * 128 + wave * 16;
        const float* ap = Hp + (size_t)(row_base + l15) * H_ + lq * 8;
        const float* ad = Hd + (size_t)(row_base + l15) * H_ + lq * 8;

        f32x4 acc[8];
        #pragma unroll
        for (int nt = 0; nt < 8; nt++) acc[nt] = (f32x4){0.f, 0.f, 0.f, 0.f};

        float4 cx0 = *(const float4*)(ap);
        float4 cx1 = *(const float4*)(ap + 4);

        #pragma unroll 1
        for (int kt = 0; kt < 8; kt++) {
            // software-pipeline: prefetch next A chunk (wave-uniform branch)
            float4 nx0 = cx0, nx1 = cx1;
            if (kt < 7) {
                int ktn = kt + 1;
                const float* pn = (ktn < 4) ? (ap + ktn * 32) : (ad + (ktn - 4) * 32);
                nx0 = *(const float4*)pn;
                nx1 = *(const float4*)(pn + 4);
            }
            short8 af = pack8(cx0, cx1);
            const unsigned short* ws = (kt < 4) ? Whs : Wds;
            const int kk = (kt & 3) * 32 + lq * 8;
            #pragma unroll
            for (int nt = 0; nt < 8; nt++) {
                short8 bf = *(const short8*)&ws[(nt * 16 + l15) * WPAD + kk];
                acc[nt] = __builtin_amdgcn_mfma_f32_16x16x32_bf16(af, bf, acc[nt], 0, 0, 0);
            }
            cx0 = nx0; cx1 = nx1;
        }

        float ep[4] = {0.f, 0.f, 0.f, 0.f};
        #pragma unroll
        for (int nt = 0; nt < 8; nt++) {
            const float wa = Was[nt * 16 + l15];
            #pragma unroll
            for (int r = 0; r < 4; r++) ep[r] += tanh_fast(acc[nt][r]) * wa;
        }
        #pragma unroll
        for (int m = 1; m < 16; m <<= 1) {
            #pragma unroll
            for (int r = 0; r < 4; r++) ep[r] += __shfl_xor(ep[r], m, 64);
        }
        if (l15 == 0) {
            // C/D: col = lane&15, row = lq*4 + r
            #pragma unroll
            for (int r = 0; r < 4; r++)
                energy[row_base + lq * 4 + r] = ep[r] + ba;
        }
    }
}

// ---------------- Phase 2: fused softmax + partial context ----------------
// grid = B*8; block (b, sl) recomputes the softmax reductions from energy/accw
// (redundant, deterministic, L2-resident) then handles t in [sl*256, sl*256+256):
// writes its alpha slice and accumulates its context partial.
__global__ __launch_bounds__(256) void softmax_ctx_kernel(
    const float* __restrict__ Hp,
    const float* __restrict__ accw,
    const float* __restrict__ beta_p,
    const float* __restrict__ energy,
    float* __restrict__ out_alpha,
    float* __restrict__ cpart)   // [B][8][H]
{
    __shared__ float al_s[T_];      // 8 KB
    __shared__ float red[8 * H_];   // 4 KB
    __shared__ float sred[8];

    const int sl   = blockIdx.x & 7;
    const int b    = blockIdx.x >> 3;
    const int tid  = threadIdx.x;
    const int lane = tid & 63;
    const int wid  = tid >> 6;   // 0..3

    const float beta_pos = log1pf(__expf(beta_p[0]));

    // ---- load energy & acc_w for all T (8 per thread, vectorized) ----
    float av[8], ev[8];
    {
        const float* pa = accw + b * T_ + tid * 8;
        const float* pe = energy + b * T_ + tid * 8;
        float4 a0 = *(const float4*)pa, a1 = *(const float4*)(pa + 4);
        float4 e0 = *(const float4*)pe, e1 = *(const float4*)(pe + 4);
        av[0]=a0.x; av[1]=a0.y; av[2]=a0.z; av[3]=a0.w;
        av[4]=a1.x; av[5]=a1.y; av[6]=a1.z; av[7]=a1.w;
        ev[0]=e0.x; ev[1]=e0.y; ev[2]=e0.z; ev[3]=e0.w;
        ev[4]=e1.x; ev[5]=e1.y; ev[6]=e1.z; ev[7]=e1.w;
    }
    float amax = -1e30f;
    #pragma unroll
    for (int i = 0; i < 8; i++) amax = fmaxf(amax, av[i]);
    for (int m = 32; m >= 1; m >>= 1) amax = fmaxf(amax, __shfl_xor(amax, m, 64));
    if (lane == 0) sred[wid] = amax;
    __syncthreads();
    if (tid == 0)
        sred[4] = fmaxf(fmaxf(sred[0], sred[1]), fmaxf(sred[2], sred[3]));
    __syncthreads();
    const float invd = beta_pos / fmaxf(sred[4], 1e-6f);

    float sv[8], smax = -1e30f;
    #pragma unroll
    for (int i = 0; i < 8; i++) {
        sv[i] = ev[i] * (1.f + av[i] * invd);
        smax = fmaxf(smax, sv[i]);
    }
    for (int m = 32; m >= 1; m >>= 1) smax = fmaxf(smax, __shfl_xor(smax, m, 64));
    __syncthreads();
    if (lane == 0) sred[wid] = smax;
    __syncthreads();
    if (tid == 0)
        sred[5] = fmaxf(fmaxf(sred[0], sred[1]), fmaxf(sred[2], sred[3]));
    __syncthreads();
    const float smax_all = sred[5];

    float p[8], psum = 0.f;
    #pragma unroll
    for (int i = 0; i < 8; i++) { p[i] = __expf(sv[i] - smax_all); psum += p[i]; }
    for (int m = 32; m >= 1; m >>= 1) psum += __shfl_xor(psum, m, 64);
    __syncthreads();
    if (lane == 0) sred[wid] = psum;
    __syncthreads();
    if (tid == 0)
        sred[6] = sred[0] + sred[1] + sred[2] + sred[3];
    __syncthreads();
    const float invS = 1.f / sred[6];

    #pragma unroll
    for (int i = 0; i < 8; i++) al_s[tid * 8 + i] = p[i] * invS;
    __syncthreads();

    // write this block's alpha slice (coalesced, each t written by exactly one block)
    out_alpha[b * T_ + sl * 256 + tid] = al_s[sl * 256 + tid];

    // ---- context partial over rows t in [sl*256, sl*256+256) ----
    const int row = tid >> 5;      // 0..7
    const int c4  = tid & 31;      // float4 index within the 128-float row

    float c0 = 0.f, c1 = 0.f, c2 = 0.f, c3 = 0.f;
    const float* base = Hp + ((size_t)b * T_ + sl * 256) * H_ + c4 * 4;
    const float* al   = al_s + sl * 256;
    #pragma unroll 4
    for (int it = 0; it < 32; it++) {
        int t = it * 8 + row;
        float a = al[t];
        float4 v = *(const float4*)(base + (size_t)t * H_);
        c0 += a * v.x; c1 += a * v.y; c2 += a * v.z; c3 += a * v.w;
    }
    red[row * H_ + c4 * 4 + 0] = c0;
    red[row * H_ + c4 * 4 + 1] = c1;
    red[row * H_ + c4 * 4 + 2] = c2;
    red[row * H_ + c4 * 4 + 3] = c3;
    __syncthreads();
    if (tid < H_) {
        float s = 0.f;
        #pragma unroll
        for (int g = 0; g < 8; g++) s += red[g * H_ + tid];
        cpart[(b * 8 + sl) * H_ + tid] = s;
    }
}

__global__ __launch_bounds__(256) void ctx_reduce_kernel(
    const float* __restrict__ cpart, float* __restrict__ out_ctx)
{
    int i = blockIdx.x * 256 + threadIdx.x;   // i < B*H
    if (i < B_ * H_) {
        int b = i >> 7, h = i & 127;
        float s = 0.f;
        #pragma unroll
        for (int g = 0; g < 8; g++) s += cpart[(b * 8 + g) * H_ + h];
        out_ctx[i] = s;
    }
}

extern "C" void kernel_launch(void* const* d_in, const int* in_sizes, int n_in,
                              void* d_out, int out_size, void* d_ws, size_t ws_size,
                              hipStream_t stream) {
    const float* Hp   = (const float*)d_in[0];
    const float* Hd   = (const float*)d_in[1];
    const float* accw = (const float*)d_in[2];
    const float* Wh   = (const float*)d_in[3];
    const float* Wd   = (const float*)d_in[4];
    const float* Wa   = (const float*)d_in[5];
    const float* ba   = (const float*)d_in[6];
    const float* beta = (const float*)d_in[7];

    float* energy_ws = (float*)d_ws;                 // B*T fp32 = 1 MB
    float* cpart_ws  = energy_ws + B_ * T_;          // B*8*H fp32 = 512 KB

    float* out_ctx   = (float*)d_out;                // [B,H]
    float* out_alpha = out_ctx + B_ * H_;            // [B,T]

    const int ntiles = (B_ * T_) / 128;   // 2048 tiles of 128 rows
    energy_kernel<<<512, 512, 0, stream>>>(Hp, Hd, Wh, Wd, Wa, ba, energy_ws, ntiles);
    softmax_ctx_kernel<<<B_ * 8, 256, 0, stream>>>(Hp, accw, beta, energy_ws, out_alpha, cpart_ws);
    ctx_reduce_kernel<<<(B_ * H_ + 255) / 256, 256, 0, stream>>>(cpart_ws, out_ctx);
}